// Round 3
// baseline (95.001 us; speedup 1.0000x reference)
//
#include <hip/hip_runtime.h>

// GATv1-style single-head attention, N=8192, F_in=128, F_out=64, alpha=0.2.
// exp(leakyrelu(s_i + d_j)) is separable per branch; predicate fl(s+d)>0 is
// exactly mono_enc(d) > mono_enc(-s). Sort j by d, prefix tables of e^d*Wh and
// e^{0.2d}*Wh sampled every 8 sorted elements, per-row ballot search + <=7
// residual terms. O(N^2 F) -> O(N(logN+F)).
// HARD CONSTRAINTS (learned r5-r8):
//   - hipLaunchCooperativeKernel aborts harness graph capture (r5).
//   - hipMemsetAsync inside kernel_launch is suspect (r6).
//   - software grid barriers deadlock -> HSA abort (r7). No grid-wide sync.
// Budget model (r9/r10 deltas reconciled): fixed harness overhead ~76-84 us
// (256 MiB ws re-poison fill(s) @ ~42 us, visible as every top-5 rocprof row);
// controllable pipeline ~10-17 us. R11: k2_sort is LDS-pipe-bound (2048
// ds_read_b128/CU); amortize each b128 over TWO owned keys -> 1024 ds/CU,
// identical u64 compares -> sorted array bitwise unchanged -> k3/k4 numerics
// untouched (absmax sits exactly at threshold; no reassociation anywhere).
// Pipeline (4 dispatches): k1_wh -> k2_sort -> k3_tables -> k4_out.

typedef unsigned long long ull;

constexpr int N_ROWS = 8192;
constexpr int F_IN   = 128;
constexpr int F_OUT  = 64;
#define LRELU_ALPHA 0.2f

constexpr int SBLK = 8;                  // prefix-table sampling granularity
constexpr int NGRP = N_ROWS / SBLK;      // 1024 groups; tables hold NGRP+1 entries

// workspace layout in floats (~3.2 MB; ws is 256 MiB). Layout kept identical
// to r8-r10 (GS* slots unused since r9).
constexpr int WS_WH   = 0;                          // Wh row-major [j][c]
constexpr int WS_ESRC = WS_WH + N_ROWS * F_OUT;     // e_src[i]
constexpr int WS_KEYA = WS_ESRC + N_ROWS;           // 8192 ull unsorted
constexpr int WS_KEYB = WS_KEYA + 2 * N_ROWS;       // 8192 ull sorted
constexpr int WS_GS1T = WS_KEYB + 2 * N_ROWS;       // (unused)
constexpr int WS_GS2T = WS_GS1T + F_OUT * NGRP;     // (unused)
constexpr int WS_GD1  = WS_GS2T + F_OUT * NGRP;     // (unused)
constexpr int WS_GD2  = WS_GD1 + NGRP;              // (unused)
constexpr int WS_P1   = WS_GD2 + NGRP;              // (NGRP+1) x 64, layout [b][c]
constexpr int WS_P2   = WS_P1 + (NGRP + 1) * F_OUT;
constexpr int WS_D1   = WS_P2 + (NGRP + 1) * F_OUT; // NGRP+1
constexpr int WS_D2   = WS_D1 + (NGRP + 1);
static_assert((WS_KEYA % 2) == 0 && (WS_KEYB % 2) == 0, "keys 8B-aligned");

// monotone float<->uint mapping (ascending uint order == ascending float order)
__device__ __forceinline__ unsigned mono_enc(float f) {
  unsigned u = __float_as_uint(f);
  return u ^ ((u & 0x80000000u) ? 0xFFFFFFFFu : 0x80000000u);
}
__device__ __forceinline__ float mono_dec(unsigned e) {
  unsigned u = e ^ ((e & 0x80000000u) ? 0x80000000u : 0xFFFFFFFFu);
  return __uint_as_float(u);
}

// ---------------- K1: Wh = h @ W ; e_src = Wh@a1 ; keys = (enc(Wh@a2), j) ----------------
// grid 512 x 256 threads. 16 rows/block, wave handles 4 rows, lane = output col. (proven)
__global__ __launch_bounds__(256) void k1_wh(const float* __restrict__ h,
                                             const float* __restrict__ W,
                                             const float* __restrict__ a,
                                             float* __restrict__ ws) {
  __shared__ float hlds[16 * F_IN];
  __shared__ float alds[2 * F_OUT];
  const int t = threadIdx.x;
  const int row0 = blockIdx.x * 16;

  const float4* hsrc = (const float4*)(h + (long)row0 * F_IN);
  float4* hd = (float4*)hlds;
  hd[t]       = hsrc[t];
  hd[t + 256] = hsrc[t + 256];
  if (t < 2 * F_OUT) alds[t] = a[t];
  __syncthreads();

  const int wave = t >> 6, lane = t & 63;
  const float* hp = hlds + (wave * 4) * F_IN;
  float acc0 = 0.f, acc1 = 0.f, acc2 = 0.f, acc3 = 0.f;

  #pragma unroll 4
  for (int k4 = 0; k4 < F_IN; k4 += 4) {
    float4 h0 = *(const float4*)(hp + k4);
    float4 h1 = *(const float4*)(hp + F_IN + k4);
    float4 h2 = *(const float4*)(hp + 2 * F_IN + k4);
    float4 h3 = *(const float4*)(hp + 3 * F_IN + k4);
    float w0 = W[(k4 + 0) * F_OUT + lane];
    float w1 = W[(k4 + 1) * F_OUT + lane];
    float w2 = W[(k4 + 2) * F_OUT + lane];
    float w3 = W[(k4 + 3) * F_OUT + lane];
    acc0 = fmaf(h0.x, w0, acc0); acc0 = fmaf(h0.y, w1, acc0);
    acc0 = fmaf(h0.z, w2, acc0); acc0 = fmaf(h0.w, w3, acc0);
    acc1 = fmaf(h1.x, w0, acc1); acc1 = fmaf(h1.y, w1, acc1);
    acc1 = fmaf(h1.z, w2, acc1); acc1 = fmaf(h1.w, w3, acc1);
    acc2 = fmaf(h2.x, w0, acc2); acc2 = fmaf(h2.y, w1, acc2);
    acc2 = fmaf(h2.z, w2, acc2); acc2 = fmaf(h2.w, w3, acc2);
    acc3 = fmaf(h3.x, w0, acc3); acc3 = fmaf(h3.y, w1, acc3);
    acc3 = fmaf(h3.z, w2, acc3); acc3 = fmaf(h3.w, w3, acc3);
  }

  const int grow = row0 + wave * 4;
  float* Wh = ws + WS_WH;
  Wh[(grow + 0) * F_OUT + lane] = acc0;
  Wh[(grow + 1) * F_OUT + lane] = acc1;
  Wh[(grow + 2) * F_OUT + lane] = acc2;
  Wh[(grow + 3) * F_OUT + lane] = acc3;

  const float a1 = alds[lane], a2 = alds[F_OUT + lane];
  float s0 = acc0 * a1, s1 = acc1 * a1, s2 = acc2 * a1, s3 = acc3 * a1;
  float d0 = acc0 * a2, d1 = acc1 * a2, d2 = acc2 * a2, d3 = acc3 * a2;
  #pragma unroll
  for (int off = 32; off; off >>= 1) {
    s0 += __shfl_down(s0, off); s1 += __shfl_down(s1, off);
    s2 += __shfl_down(s2, off); s3 += __shfl_down(s3, off);
    d0 += __shfl_down(d0, off); d1 += __shfl_down(d1, off);
    d2 += __shfl_down(d2, off); d3 += __shfl_down(d3, off);
  }
  if (lane == 0) {
    ws[WS_ESRC + grow + 0] = s0; ws[WS_ESRC + grow + 1] = s1;
    ws[WS_ESRC + grow + 2] = s2; ws[WS_ESRC + grow + 3] = s3;
    ull* keys = (ull*)(ws + WS_KEYA);
    keys[grow + 0] = ((ull)mono_enc(d0) << 32) | (unsigned)(grow + 0);
    keys[grow + 1] = ((ull)mono_enc(d1) << 32) | (unsigned)(grow + 1);
    keys[grow + 2] = ((ull)mono_enc(d2) << 32) | (unsigned)(grow + 2);
    keys[grow + 3] = ((ull)mono_enc(d3) << 32) | (unsigned)(grow + 3);
  }
}

// ---------------- K2 (r11): O(N^2) counting rank-sort, 2 keys per b128 read --------------
// 256 blocks x 256 threads (1 block/CU). All 8192 keys staged in LDS (64 KB). Block owns
// 32 keys: slot = t>>4 in [0,16) owns keys blk*32 + 2*slot + {0,1}; slice s = t&15 scans
// pairs p = 16*i + s (b128 = 2 keys) and compares BOTH elements against BOTH owned keys
// -> each ds_read serves 4 compares (ds insts/CU halved vs r10: 2048 -> 1024).
// Bank math per wave-inst: addr depends only on s -> 16 distinct 16-B addrs, 4-way lane
// broadcast; byte 256i+16s -> bank-quad (4s)%32 -> 2 addrs/quad = 2-way = free (m136).
// rank = strict-< u64 count over all keys (unique: low 32 bits = j) -> dst[rank] = key is
// an exact permutation, bitwise identical to r10's sorted array.
__global__ __launch_bounds__(256) void k2_sort(const ull* __restrict__ src,
                                               ull* __restrict__ dst) {
  __shared__ ull lk[8192];          // 64 KB — all keys
  const int t = threadIdx.x;        // 0..255

  ulonglong2* lkv = (ulonglong2*)lk;
  const ulonglong2* srcv = (const ulonglong2*)src;
  #pragma unroll
  for (int c = 0; c < 16; ++c) lkv[c * 256 + t] = srcv[c * 256 + t];
  __syncthreads();

  const int slot = t >> 4;                          // 0..15
  const int s    = t & 15;                          // slice
  const int kidx = (blockIdx.x << 5) + (slot << 1); // 2 owned keys
  const ull key0 = lk[kidx];
  const ull key1 = lk[kidx + 1];

  int cnt0 = 0, cnt1 = 0;
  const ulonglong2* lk2 = (const ulonglong2*)lk;    // 4096 pairs
  #pragma unroll 8
  for (int i = 0; i < 256; ++i) {
    ulonglong2 v = lk2[(i << 4) | s];
    cnt0 += (v.x < key0) ? 1 : 0;
    cnt0 += (v.y < key0) ? 1 : 0;
    cnt1 += (v.x < key1) ? 1 : 0;
    cnt1 += (v.y < key1) ? 1 : 0;
  }
  // reduce the 16 slice partials (16-lane groups within the wave)
  cnt0 += __shfl_down(cnt0, 8, 16); cnt1 += __shfl_down(cnt1, 8, 16);
  cnt0 += __shfl_down(cnt0, 4, 16); cnt1 += __shfl_down(cnt1, 4, 16);
  cnt0 += __shfl_down(cnt0, 2, 16); cnt1 += __shfl_down(cnt1, 2, 16);
  cnt0 += __shfl_down(cnt0, 1, 16); cnt1 += __shfl_down(cnt1, 1, 16);
  if (s == 0) {                      // cnt = exact global rank in [0, 8192)
    dst[cnt0] = key0;
    dst[cnt1] = key1;
  }
}

// ---------------- K3: fused group sums + dual in-block scan -> P1,P2,D1,D2 (r9 proven) ---
// 65 blocks x 1024 threads. Blocks 0..63: column c = blk. Thread t = group g: reads the
// group's 8 sorted keys and gathers Wh[j][c] (L2-resident). Dual Hillis-Steele scan kept
// BITWISE IDENTICAL to the proven version (absmax sits at threshold; no reassociation).
__global__ __launch_bounds__(1024) void k3_tables(float* __restrict__ ws) {
  __shared__ float sa[1024];
  __shared__ float sb[1024];
  const int t = threadIdx.x;
  const int blk = blockIdx.x;
  const ull* K = (const ull*)(ws + WS_KEYB);
  const float* Wh = ws + WS_WH;

  float s1 = 0.f, s2 = 0.f;
  if (blk < 64) {
    const int c = blk;
    const ull* kp = K + (t << 3);
    #pragma unroll
    for (int o = 0; o < SBLK; ++o) {
      ull key = kp[o];
      float d = mono_dec((unsigned)(key >> 32));
      int j = (int)(key & 0xFFFFFFFFu);
      float e1 = __expf(d), e2 = __expf(LRELU_ALPHA * d);
      float v = Wh[j * F_OUT + c];
      s1 = fmaf(e1, v, s1); s2 = fmaf(e2, v, s2);
    }
  } else {
    const ull* kp = K + (t << 3);
    #pragma unroll
    for (int o = 0; o < SBLK; ++o) {
      ull key = kp[o];
      float d = mono_dec((unsigned)(key >> 32));
      s1 += __expf(d); s2 += __expf(LRELU_ALPHA * d);
    }
  }

  const float xa = s1, xb = s2;
  sa[t] = xa; sb[t] = xb;
  __syncthreads();
  for (int off = 1; off < 1024; off <<= 1) {   // Hillis-Steele inclusive scan (x2)
    float ya = (t >= off) ? sa[t - off] : 0.f;
    float yb = (t >= off) ? sb[t - off] : 0.f;
    __syncthreads();
    sa[t] += ya; sb[t] += yb;
    __syncthreads();
  }
  const float ia = sa[t], ib = sb[t];
  const float ea = ia - xa, eb = ib - xb;

  if (blk < 64) {
    const int c = blk;
    ws[WS_P1 + t * F_OUT + c] = ea;
    ws[WS_P2 + t * F_OUT + c] = eb;
    if (t == NGRP - 1) {
      ws[WS_P1 + NGRP * F_OUT + c] = ia;
      ws[WS_P2 + NGRP * F_OUT + c] = ib;
    }
  } else {
    ws[WS_D1 + t] = ea;
    ws[WS_D2 + t] = eb;
    if (t == NGRP - 1) {
      ws[WS_D1 + NGRP] = ia;
      ws[WS_D2 + NGRP] = ib;
    }
  }
}

// ---------------- K4: 3-stage wave-ballot search + table lookup + residual + ELU ---------
// grid 2048 x 256. One wave per row, lane = output column. (proven)
__global__ __launch_bounds__(256) void k4_out(const float* __restrict__ ws,
                                              float* __restrict__ out) {
  const int t = threadIdx.x, wv = t >> 6, lane = t & 63;
  const int i = blockIdx.x * 4 + wv;
  const ull* K = (const ull*)(ws + WS_KEYB);
  const float s = ws[WS_ESRC + i];
  const float ns = (s == 0.0f) ? 0.0f : -s;   // canonicalize -0
  const unsigned Ki = mono_enc(ns);           // m > Ki  <=>  fl(s+d) > 0

  unsigned m1 = (unsigned)(K[lane << 7] >> 32);
  ull bal1 = __ballot(m1 <= Ki);
  int tl;
  if (bal1 == 0ull) {
    tl = 0;
  } else {
    int L1 = 63 - __clzll((long long)bal1);
    int base = L1 << 7;
    unsigned m2 = (unsigned)(K[base + (lane << 1)] >> 32);
    ull bal2 = __ballot(m2 <= Ki);
    int L2 = 63 - __clzll((long long)bal2);
    int p = base + (L2 << 1) + 1;
    unsigned m3 = (unsigned)(K[p] >> 32);
    tl = p + ((m3 <= Ki) ? 1 : 0);
  }
  const int b = tl >> 3, rr = tl & 7;

  float p1 = ws[WS_P1 + b * F_OUT + lane];
  float p2 = ws[WS_P2 + b * F_OUT + lane];
  float d1 = ws[WS_D1 + b], d2 = ws[WS_D2 + b];
  const float p1tot = ws[WS_P1 + NGRP * F_OUT + lane];
  const float d1tot = ws[WS_D1 + NGRP];
  const float* Wh = ws + WS_WH;

  for (int o = 0; o < rr; ++o) {               // <=7 residual elements
    ull key = K[(b << 3) + o];
    float d = mono_dec((unsigned)(key >> 32));
    int j = (int)(key & 0xFFFFFFFFu);
    float e1 = __expf(d), e2 = __expf(LRELU_ALPHA * d);
    float v = Wh[j * F_OUT + lane];            // coalesced 256B row
    p1 = fmaf(e1, v, p1); p2 = fmaf(e2, v, p2);
    d1 += e1; d2 += e2;
  }

  const float es1 = __expf(s), es2 = __expf(LRELU_ALPHA * s);
  const float num = es1 * (p1tot - p1) + es2 * p2;
  const float den = es1 * (d1tot - d1) + es2 * d2;
  const float r = num / den;
  out[i * F_OUT + lane] = (r > 0.f) ? r : (__expf(r) - 1.f);
}

extern "C" void kernel_launch(void* const* d_in, const int* in_sizes, int n_in,
                              void* d_out, int out_size, void* d_ws, size_t ws_size,
                              hipStream_t stream) {
  const float* h = (const float*)d_in[0];
  const float* W = (const float*)d_in[1];
  const float* a = (const float*)d_in[2];
  float* ws = (float*)d_ws;
  float* out = (float*)d_out;
  ull* keyA = (ull*)(ws + WS_KEYA);
  ull* keyB = (ull*)(ws + WS_KEYB);

  hipLaunchKernelGGL(k1_wh,     dim3(N_ROWS / 16), dim3(256),  0, stream, h, W, a, ws);
  hipLaunchKernelGGL(k2_sort,   dim3(256),         dim3(256),  0, stream, keyA, keyB);
  hipLaunchKernelGGL(k3_tables, dim3(65),          dim3(1024), 0, stream, ws);
  hipLaunchKernelGGL(k4_out,    dim3(N_ROWS / 4),  dim3(256),  0, stream, ws, out);
}

// Round 4
// 92.440 us; speedup vs baseline: 1.0277x; 1.0277x over previous
//
#include <hip/hip_runtime.h>

// GATv1-style single-head attention, N=8192, F_in=128, F_out=64, alpha=0.2.
// exp(leakyrelu(s_i + d_j)) is separable per branch; predicate fl(s+d)>0 is
// exactly mono_enc(d) > mono_enc(-s). Sort j by d, prefix tables of e^d*Wh and
// e^{0.2d}*Wh sampled every 8 sorted elements, per-row ballot search + <=7
// residual terms. O(N^2 F) -> O(N(logN+F)).
// HARD CONSTRAINTS (learned r5-r8):
//   - hipLaunchCooperativeKernel aborts harness graph capture (r5).
//   - hipMemsetAsync inside kernel_launch is suspect (r6).
//   - software grid barriers deadlock -> HSA abort (r7). No grid-wide sync.
// Budget model (r9-r11): fixed harness overhead ~82 us (256 MiB ws re-poison
// fills @ ~41 us each, always the top rocprof rows); controllable ~12 us.
// R11 lesson: 2-keys-per-ds_read flipped k2 to VALU-bound (+1.2 us) -> REVERTED
// to r10's proven 512-thread k2. R12: k3's scan had 20 full-block barriers
// (16 waves) with ~3 instrs between them; ping-pong buffers need only 1
// barrier/round (10 total) and perform THE SAME additions in THE SAME order
// -> bitwise-identical tables (absmax sits exactly at threshold).
// Pipeline (4 dispatches): k1_wh -> k2_sort -> k3_tables -> k4_out.

typedef unsigned long long ull;

constexpr int N_ROWS = 8192;
constexpr int F_IN   = 128;
constexpr int F_OUT  = 64;
#define LRELU_ALPHA 0.2f

constexpr int SBLK = 8;                  // prefix-table sampling granularity
constexpr int NGRP = N_ROWS / SBLK;      // 1024 groups; tables hold NGRP+1 entries

// workspace layout in floats (~3.2 MB; ws is 256 MiB). Layout kept identical
// to r8-r11 (GS* slots unused since r9).
constexpr int WS_WH   = 0;                          // Wh row-major [j][c]
constexpr int WS_ESRC = WS_WH + N_ROWS * F_OUT;     // e_src[i]
constexpr int WS_KEYA = WS_ESRC + N_ROWS;           // 8192 ull unsorted
constexpr int WS_KEYB = WS_KEYA + 2 * N_ROWS;       // 8192 ull sorted
constexpr int WS_GS1T = WS_KEYB + 2 * N_ROWS;       // (unused)
constexpr int WS_GS2T = WS_GS1T + F_OUT * NGRP;     // (unused)
constexpr int WS_GD1  = WS_GS2T + F_OUT * NGRP;     // (unused)
constexpr int WS_GD2  = WS_GD1 + NGRP;              // (unused)
constexpr int WS_P1   = WS_GD2 + NGRP;              // (NGRP+1) x 64, layout [b][c]
constexpr int WS_P2   = WS_P1 + (NGRP + 1) * F_OUT;
constexpr int WS_D1   = WS_P2 + (NGRP + 1) * F_OUT; // NGRP+1
constexpr int WS_D2   = WS_D1 + (NGRP + 1);
static_assert((WS_KEYA % 2) == 0 && (WS_KEYB % 2) == 0, "keys 8B-aligned");

// monotone float<->uint mapping (ascending uint order == ascending float order)
__device__ __forceinline__ unsigned mono_enc(float f) {
  unsigned u = __float_as_uint(f);
  return u ^ ((u & 0x80000000u) ? 0xFFFFFFFFu : 0x80000000u);
}
__device__ __forceinline__ float mono_dec(unsigned e) {
  unsigned u = e ^ ((e & 0x80000000u) ? 0x80000000u : 0xFFFFFFFFu);
  return __uint_as_float(u);
}

// ---------------- K1: Wh = h @ W ; e_src = Wh@a1 ; keys = (enc(Wh@a2), j) ----------------
// grid 512 x 256 threads. 16 rows/block, wave handles 4 rows, lane = output col. (proven)
__global__ __launch_bounds__(256) void k1_wh(const float* __restrict__ h,
                                             const float* __restrict__ W,
                                             const float* __restrict__ a,
                                             float* __restrict__ ws) {
  __shared__ float hlds[16 * F_IN];
  __shared__ float alds[2 * F_OUT];
  const int t = threadIdx.x;
  const int row0 = blockIdx.x * 16;

  const float4* hsrc = (const float4*)(h + (long)row0 * F_IN);
  float4* hd = (float4*)hlds;
  hd[t]       = hsrc[t];
  hd[t + 256] = hsrc[t + 256];
  if (t < 2 * F_OUT) alds[t] = a[t];
  __syncthreads();

  const int wave = t >> 6, lane = t & 63;
  const float* hp = hlds + (wave * 4) * F_IN;
  float acc0 = 0.f, acc1 = 0.f, acc2 = 0.f, acc3 = 0.f;

  #pragma unroll 4
  for (int k4 = 0; k4 < F_IN; k4 += 4) {
    float4 h0 = *(const float4*)(hp + k4);
    float4 h1 = *(const float4*)(hp + F_IN + k4);
    float4 h2 = *(const float4*)(hp + 2 * F_IN + k4);
    float4 h3 = *(const float4*)(hp + 3 * F_IN + k4);
    float w0 = W[(k4 + 0) * F_OUT + lane];
    float w1 = W[(k4 + 1) * F_OUT + lane];
    float w2 = W[(k4 + 2) * F_OUT + lane];
    float w3 = W[(k4 + 3) * F_OUT + lane];
    acc0 = fmaf(h0.x, w0, acc0); acc0 = fmaf(h0.y, w1, acc0);
    acc0 = fmaf(h0.z, w2, acc0); acc0 = fmaf(h0.w, w3, acc0);
    acc1 = fmaf(h1.x, w0, acc1); acc1 = fmaf(h1.y, w1, acc1);
    acc1 = fmaf(h1.z, w2, acc1); acc1 = fmaf(h1.w, w3, acc1);
    acc2 = fmaf(h2.x, w0, acc2); acc2 = fmaf(h2.y, w1, acc2);
    acc2 = fmaf(h2.z, w2, acc2); acc2 = fmaf(h2.w, w3, acc2);
    acc3 = fmaf(h3.x, w0, acc3); acc3 = fmaf(h3.y, w1, acc3);
    acc3 = fmaf(h3.z, w2, acc3); acc3 = fmaf(h3.w, w3, acc3);
  }

  const int grow = row0 + wave * 4;
  float* Wh = ws + WS_WH;
  Wh[(grow + 0) * F_OUT + lane] = acc0;
  Wh[(grow + 1) * F_OUT + lane] = acc1;
  Wh[(grow + 2) * F_OUT + lane] = acc2;
  Wh[(grow + 3) * F_OUT + lane] = acc3;

  const float a1 = alds[lane], a2 = alds[F_OUT + lane];
  float s0 = acc0 * a1, s1 = acc1 * a1, s2 = acc2 * a1, s3 = acc3 * a1;
  float d0 = acc0 * a2, d1 = acc1 * a2, d2 = acc2 * a2, d3 = acc3 * a2;
  #pragma unroll
  for (int off = 32; off; off >>= 1) {
    s0 += __shfl_down(s0, off); s1 += __shfl_down(s1, off);
    s2 += __shfl_down(s2, off); s3 += __shfl_down(s3, off);
    d0 += __shfl_down(d0, off); d1 += __shfl_down(d1, off);
    d2 += __shfl_down(d2, off); d3 += __shfl_down(d3, off);
  }
  if (lane == 0) {
    ws[WS_ESRC + grow + 0] = s0; ws[WS_ESRC + grow + 1] = s1;
    ws[WS_ESRC + grow + 2] = s2; ws[WS_ESRC + grow + 3] = s3;
    ull* keys = (ull*)(ws + WS_KEYA);
    keys[grow + 0] = ((ull)mono_enc(d0) << 32) | (unsigned)(grow + 0);
    keys[grow + 1] = ((ull)mono_enc(d1) << 32) | (unsigned)(grow + 1);
    keys[grow + 2] = ((ull)mono_enc(d2) << 32) | (unsigned)(grow + 2);
    keys[grow + 3] = ((ull)mono_enc(d3) << 32) | (unsigned)(grow + 3);
  }
}

// ---------------- K2 (r10, proven 93.8): O(N^2) counting rank-sort ------------------------
// 256 blocks x 512 threads. All 8192 keys staged in LDS (64 KB). Block owns 32 keys:
// key idx = blk*32 + (t>>4); slice s = t&15 counts key-pairs p = 16*i + s, i = 0..255
// (b128 read of 2 keys). Bank math: pair p -> byte 16p -> bank-quad 4s%32: 16 slices map
// to 8 quads x 2 addresses = 2-way (free, m136); the 4 lanes sharing s broadcast.
// rank = strict-< count over all keys (unique: low 32 bits = j) -> dst[rank] = key is an
// exact permutation, bitwise-identical to any correct sort of the same keys.
__global__ __launch_bounds__(512) void k2_sort(const ull* __restrict__ src,
                                               ull* __restrict__ dst) {
  __shared__ ull lk[8192];          // 64 KB — all keys
  const int t = threadIdx.x;        // 0..511

  ulonglong2* lkv = (ulonglong2*)lk;
  const ulonglong2* srcv = (const ulonglong2*)src;
  #pragma unroll
  for (int c = 0; c < 8; ++c) lkv[c * 512 + t] = srcv[c * 512 + t];
  __syncthreads();

  const int kidx = (blockIdx.x << 5) + (t >> 4);   // 32 keys per block
  const ull key = lk[kidx];
  const int s = t & 15;

  int cnt = 0;
  const ulonglong2* lk2 = (const ulonglong2*)lk;   // 4096 pairs
  #pragma unroll 8
  for (int i = 0; i < 256; ++i) {
    ulonglong2 v = lk2[(i << 4) | s];
    cnt += (v.x < key) ? 1 : 0;
    cnt += (v.y < key) ? 1 : 0;
  }
  // reduce the 16 slice partials (16-lane groups within the wave)
  cnt += __shfl_down(cnt, 8, 16);
  cnt += __shfl_down(cnt, 4, 16);
  cnt += __shfl_down(cnt, 2, 16);
  cnt += __shfl_down(cnt, 1, 16);
  if (s == 0) dst[cnt] = key;       // cnt = exact global rank in [0, 8192)
}

// ---------------- K3 (r12): fused group sums + dual PING-PONG scan -> P1,P2,D1,D2 --------
// 65 blocks x 1024 threads. Blocks 0..63: column c = blk; thread t = group g reads the
// group's 8 sorted keys (vectorized 4x ulonglong2, consumed in the same o=0..7 order) and
// gathers Wh[j][c] (L2-resident). Block 64: denominators. Scan: ping-pong buffers ->
// ONE barrier per round (10 vs 20); dst[t] = src[t] + src[t-off] performs exactly the
// additions of the in-place Hillis-Steele in the same order -> tables bitwise unchanged.
__global__ __launch_bounds__(1024) void k3_tables(float* __restrict__ ws) {
  __shared__ float sa[2][1024];
  __shared__ float sb[2][1024];
  const int t = threadIdx.x;
  const int blk = blockIdx.x;
  const ull* K = (const ull*)(ws + WS_KEYB);
  const float* Wh = ws + WS_WH;

  ull k8[8];
  {
    const ulonglong2* kp2 = (const ulonglong2*)(K + (t << 3));
    ulonglong2 q0 = kp2[0], q1 = kp2[1], q2 = kp2[2], q3 = kp2[3];
    k8[0] = q0.x; k8[1] = q0.y; k8[2] = q1.x; k8[3] = q1.y;
    k8[4] = q2.x; k8[5] = q2.y; k8[6] = q3.x; k8[7] = q3.y;
  }

  float s1 = 0.f, s2 = 0.f;
  if (blk < 64) {
    const int c = blk;
    #pragma unroll
    for (int o = 0; o < SBLK; ++o) {
      ull key = k8[o];
      float d = mono_dec((unsigned)(key >> 32));
      int j = (int)(key & 0xFFFFFFFFu);
      float e1 = __expf(d), e2 = __expf(LRELU_ALPHA * d);
      float v = Wh[j * F_OUT + c];
      s1 = fmaf(e1, v, s1); s2 = fmaf(e2, v, s2);
    }
  } else {
    #pragma unroll
    for (int o = 0; o < SBLK; ++o) {
      ull key = k8[o];
      float d = mono_dec((unsigned)(key >> 32));
      s1 += __expf(d); s2 += __expf(LRELU_ALPHA * d);
    }
  }

  const float xa = s1, xb = s2;
  sa[0][t] = xa; sb[0][t] = xb;
  __syncthreads();
  int cur = 0;
  #pragma unroll
  for (int off = 1; off < 1024; off <<= 1) {   // 10 rounds, 1 barrier each
    float va = sa[cur][t], vb = sb[cur][t];
    if (t >= off) { va += sa[cur][t - off]; vb += sb[cur][t - off]; }
    sa[cur ^ 1][t] = va;
    sb[cur ^ 1][t] = vb;
    __syncthreads();
    cur ^= 1;
  }
  const float ia = sa[cur][t], ib = sb[cur][t];
  const float ea = ia - xa, eb = ib - xb;

  if (blk < 64) {
    const int c = blk;
    ws[WS_P1 + t * F_OUT + c] = ea;
    ws[WS_P2 + t * F_OUT + c] = eb;
    if (t == NGRP - 1) {
      ws[WS_P1 + NGRP * F_OUT + c] = ia;
      ws[WS_P2 + NGRP * F_OUT + c] = ib;
    }
  } else {
    ws[WS_D1 + t] = ea;
    ws[WS_D2 + t] = eb;
    if (t == NGRP - 1) {
      ws[WS_D1 + NGRP] = ia;
      ws[WS_D2 + NGRP] = ib;
    }
  }
}

// ---------------- K4: 3-stage wave-ballot search + table lookup + residual + ELU ---------
// grid 2048 x 256. One wave per row, lane = output column. (proven)
__global__ __launch_bounds__(256) void k4_out(const float* __restrict__ ws,
                                              float* __restrict__ out) {
  const int t = threadIdx.x, wv = t >> 6, lane = t & 63;
  const int i = blockIdx.x * 4 + wv;
  const ull* K = (const ull*)(ws + WS_KEYB);
  const float s = ws[WS_ESRC + i];
  const float ns = (s == 0.0f) ? 0.0f : -s;   // canonicalize -0
  const unsigned Ki = mono_enc(ns);           // m > Ki  <=>  fl(s+d) > 0

  unsigned m1 = (unsigned)(K[lane << 7] >> 32);
  ull bal1 = __ballot(m1 <= Ki);
  int tl;
  if (bal1 == 0ull) {
    tl = 0;
  } else {
    int L1 = 63 - __clzll((long long)bal1);
    int base = L1 << 7;
    unsigned m2 = (unsigned)(K[base + (lane << 1)] >> 32);
    ull bal2 = __ballot(m2 <= Ki);
    int L2 = 63 - __clzll((long long)bal2);
    int p = base + (L2 << 1) + 1;
    unsigned m3 = (unsigned)(K[p] >> 32);
    tl = p + ((m3 <= Ki) ? 1 : 0);
  }
  const int b = tl >> 3, rr = tl & 7;

  float p1 = ws[WS_P1 + b * F_OUT + lane];
  float p2 = ws[WS_P2 + b * F_OUT + lane];
  float d1 = ws[WS_D1 + b], d2 = ws[WS_D2 + b];
  const float p1tot = ws[WS_P1 + NGRP * F_OUT + lane];
  const float d1tot = ws[WS_D1 + NGRP];
  const float* Wh = ws + WS_WH;

  for (int o = 0; o < rr; ++o) {               // <=7 residual elements
    ull key = K[(b << 3) + o];
    float d = mono_dec((unsigned)(key >> 32));
    int j = (int)(key & 0xFFFFFFFFu);
    float e1 = __expf(d), e2 = __expf(LRELU_ALPHA * d);
    float v = Wh[j * F_OUT + lane];            // coalesced 256B row
    p1 = fmaf(e1, v, p1); p2 = fmaf(e2, v, p2);
    d1 += e1; d2 += e2;
  }

  const float es1 = __expf(s), es2 = __expf(LRELU_ALPHA * s);
  const float num = es1 * (p1tot - p1) + es2 * p2;
  const float den = es1 * (d1tot - d1) + es2 * d2;
  const float r = num / den;
  out[i * F_OUT + lane] = (r > 0.f) ? r : (__expf(r) - 1.f);
}

extern "C" void kernel_launch(void* const* d_in, const int* in_sizes, int n_in,
                              void* d_out, int out_size, void* d_ws, size_t ws_size,
                              hipStream_t stream) {
  const float* h = (const float*)d_in[0];
  const float* W = (const float*)d_in[1];
  const float* a = (const float*)d_in[2];
  float* ws = (float*)d_ws;
  float* out = (float*)d_out;
  ull* keyA = (ull*)(ws + WS_KEYA);
  ull* keyB = (ull*)(ws + WS_KEYB);

  hipLaunchKernelGGL(k1_wh,     dim3(N_ROWS / 16), dim3(256),  0, stream, h, W, a, ws);
  hipLaunchKernelGGL(k2_sort,   dim3(256),         dim3(512),  0, stream, keyA, keyB);
  hipLaunchKernelGGL(k3_tables, dim3(65),          dim3(1024), 0, stream, ws);
  hipLaunchKernelGGL(k4_out,    dim3(N_ROWS / 4),  dim3(256),  0, stream, ws, out);
}

// Round 5
// 92.228 us; speedup vs baseline: 1.0301x; 1.0023x over previous
//
#include <hip/hip_runtime.h>

// GATv1-style single-head attention, N=8192, F_in=128, F_out=64, alpha=0.2.
// exp(leakyrelu(s_i + d_j)) is separable per branch; predicate fl(s+d)>0 is
// exactly mono_enc(d) > mono_enc(-s). Sort j by d, prefix tables of e^d*Wh and
// e^{0.2d}*Wh sampled every 8 sorted elements, per-row ballot search + <=7
// residual terms. O(N^2 F) -> O(N(logN+F)).
// HARD CONSTRAINTS (learned r5-r8):
//   - hipLaunchCooperativeKernel aborts harness graph capture (r5).
//   - hipMemsetAsync inside kernel_launch is suspect (r6).
//   - software grid barriers deadlock -> HSA abort (r7). No grid-wide sync.
// Budget model (r9-r12): timed window contains ~83 us of harness ws re-poison
// fills (2 x 41.5 us, always the top rocprof rows); controllable ~9.4 us
// (k1 ~2, k2 ~3, k3 ~1.8, k4 ~1.3, gaps ~1.3).
// R11 lesson: amortizing k2 reads at 256 threads dropped occupancy to
// 1 wave/SIMD -> latency-exposed (+1.2 us). R13: amortize while KEEPING
// 8 waves: 2 owned keys/thread x 32 slices -> ds instrs/CU 2048 -> 1024 and
// less per-compare loop overhead; same strict-< u64 compares -> sorted array
// bitwise unchanged -> k3/k4 numerics untouched (absmax sits at threshold).
// Pipeline (4 dispatches): k1_wh -> k2_sort -> k3_tables -> k4_out.

typedef unsigned long long ull;

constexpr int N_ROWS = 8192;
constexpr int F_IN   = 128;
constexpr int F_OUT  = 64;
#define LRELU_ALPHA 0.2f

constexpr int SBLK = 8;                  // prefix-table sampling granularity
constexpr int NGRP = N_ROWS / SBLK;      // 1024 groups; tables hold NGRP+1 entries

// workspace layout in floats (~3.2 MB; ws is 256 MiB). Layout kept identical
// to r8-r12 (GS* slots unused since r9).
constexpr int WS_WH   = 0;                          // Wh row-major [j][c]
constexpr int WS_ESRC = WS_WH + N_ROWS * F_OUT;     // e_src[i]
constexpr int WS_KEYA = WS_ESRC + N_ROWS;           // 8192 ull unsorted
constexpr int WS_KEYB = WS_KEYA + 2 * N_ROWS;       // 8192 ull sorted
constexpr int WS_GS1T = WS_KEYB + 2 * N_ROWS;       // (unused)
constexpr int WS_GS2T = WS_GS1T + F_OUT * NGRP;     // (unused)
constexpr int WS_GD1  = WS_GS2T + F_OUT * NGRP;     // (unused)
constexpr int WS_GD2  = WS_GD1 + NGRP;              // (unused)
constexpr int WS_P1   = WS_GD2 + NGRP;              // (NGRP+1) x 64, layout [b][c]
constexpr int WS_P2   = WS_P1 + (NGRP + 1) * F_OUT;
constexpr int WS_D1   = WS_P2 + (NGRP + 1) * F_OUT; // NGRP+1
constexpr int WS_D2   = WS_D1 + (NGRP + 1);
static_assert((WS_KEYA % 2) == 0 && (WS_KEYB % 2) == 0, "keys 8B-aligned");

// monotone float<->uint mapping (ascending uint order == ascending float order)
__device__ __forceinline__ unsigned mono_enc(float f) {
  unsigned u = __float_as_uint(f);
  return u ^ ((u & 0x80000000u) ? 0xFFFFFFFFu : 0x80000000u);
}
__device__ __forceinline__ float mono_dec(unsigned e) {
  unsigned u = e ^ ((e & 0x80000000u) ? 0x80000000u : 0xFFFFFFFFu);
  return __uint_as_float(u);
}

// ---------------- K1: Wh = h @ W ; e_src = Wh@a1 ; keys = (enc(Wh@a2), j) ----------------
// grid 512 x 256 threads. 16 rows/block, wave handles 4 rows, lane = output col. (proven)
__global__ __launch_bounds__(256) void k1_wh(const float* __restrict__ h,
                                             const float* __restrict__ W,
                                             const float* __restrict__ a,
                                             float* __restrict__ ws) {
  __shared__ float hlds[16 * F_IN];
  __shared__ float alds[2 * F_OUT];
  const int t = threadIdx.x;
  const int row0 = blockIdx.x * 16;

  const float4* hsrc = (const float4*)(h + (long)row0 * F_IN);
  float4* hd = (float4*)hlds;
  hd[t]       = hsrc[t];
  hd[t + 256] = hsrc[t + 256];
  if (t < 2 * F_OUT) alds[t] = a[t];
  __syncthreads();

  const int wave = t >> 6, lane = t & 63;
  const float* hp = hlds + (wave * 4) * F_IN;
  float acc0 = 0.f, acc1 = 0.f, acc2 = 0.f, acc3 = 0.f;

  #pragma unroll 4
  for (int k4 = 0; k4 < F_IN; k4 += 4) {
    float4 h0 = *(const float4*)(hp + k4);
    float4 h1 = *(const float4*)(hp + F_IN + k4);
    float4 h2 = *(const float4*)(hp + 2 * F_IN + k4);
    float4 h3 = *(const float4*)(hp + 3 * F_IN + k4);
    float w0 = W[(k4 + 0) * F_OUT + lane];
    float w1 = W[(k4 + 1) * F_OUT + lane];
    float w2 = W[(k4 + 2) * F_OUT + lane];
    float w3 = W[(k4 + 3) * F_OUT + lane];
    acc0 = fmaf(h0.x, w0, acc0); acc0 = fmaf(h0.y, w1, acc0);
    acc0 = fmaf(h0.z, w2, acc0); acc0 = fmaf(h0.w, w3, acc0);
    acc1 = fmaf(h1.x, w0, acc1); acc1 = fmaf(h1.y, w1, acc1);
    acc1 = fmaf(h1.z, w2, acc1); acc1 = fmaf(h1.w, w3, acc1);
    acc2 = fmaf(h2.x, w0, acc2); acc2 = fmaf(h2.y, w1, acc2);
    acc2 = fmaf(h2.z, w2, acc2); acc2 = fmaf(h2.w, w3, acc2);
    acc3 = fmaf(h3.x, w0, acc3); acc3 = fmaf(h3.y, w1, acc3);
    acc3 = fmaf(h3.z, w2, acc3); acc3 = fmaf(h3.w, w3, acc3);
  }

  const int grow = row0 + wave * 4;
  float* Wh = ws + WS_WH;
  Wh[(grow + 0) * F_OUT + lane] = acc0;
  Wh[(grow + 1) * F_OUT + lane] = acc1;
  Wh[(grow + 2) * F_OUT + lane] = acc2;
  Wh[(grow + 3) * F_OUT + lane] = acc3;

  const float a1 = alds[lane], a2 = alds[F_OUT + lane];
  float s0 = acc0 * a1, s1 = acc1 * a1, s2 = acc2 * a1, s3 = acc3 * a1;
  float d0 = acc0 * a2, d1 = acc1 * a2, d2 = acc2 * a2, d3 = acc3 * a2;
  #pragma unroll
  for (int off = 32; off; off >>= 1) {
    s0 += __shfl_down(s0, off); s1 += __shfl_down(s1, off);
    s2 += __shfl_down(s2, off); s3 += __shfl_down(s3, off);
    d0 += __shfl_down(d0, off); d1 += __shfl_down(d1, off);
    d2 += __shfl_down(d2, off); d3 += __shfl_down(d3, off);
  }
  if (lane == 0) {
    ws[WS_ESRC + grow + 0] = s0; ws[WS_ESRC + grow + 1] = s1;
    ws[WS_ESRC + grow + 2] = s2; ws[WS_ESRC + grow + 3] = s3;
    ull* keys = (ull*)(ws + WS_KEYA);
    keys[grow + 0] = ((ull)mono_enc(d0) << 32) | (unsigned)(grow + 0);
    keys[grow + 1] = ((ull)mono_enc(d1) << 32) | (unsigned)(grow + 1);
    keys[grow + 2] = ((ull)mono_enc(d2) << 32) | (unsigned)(grow + 2);
    keys[grow + 3] = ((ull)mono_enc(d3) << 32) | (unsigned)(grow + 3);
  }
}

// ---------------- K2 (r13): O(N^2) counting rank-sort, 2 keys/thread @ 8 waves -----------
// 256 blocks x 512 threads (1 block/CU, 2 waves/SIMD — occupancy kept, r11 lesson).
// All 8192 keys staged in LDS (64 KB). slot = t>>5 in [0,16) owns keys
// blk*32 + 2*slot + {0,1}; slice s = t&31 scans pairs p = 32*i + s (b128 = 2 keys),
// i = 0..127, comparing both elements vs both owned keys -> each ds_read serves
// 4 compares (ds instrs/CU: 2048 -> 1024; per-compare loop/addr VALU also halves).
// Wave-instr addr pattern: lanes 0-31 = slot A slices 0-31, lanes 32-63 = slot B same
// slices -> 32 distinct 16-B addrs x 2-lane broadcast (512 B distinct, ~2 LDS cyc).
// rank = strict-< u64 count over all keys (unique: low 32 bits = j) -> dst[rank] = key
// is an exact permutation, bitwise identical to r10/r12's sorted array.
__global__ __launch_bounds__(512) void k2_sort(const ull* __restrict__ src,
                                               ull* __restrict__ dst) {
  __shared__ ull lk[8192];          // 64 KB — all keys
  const int t = threadIdx.x;        // 0..511

  ulonglong2* lkv = (ulonglong2*)lk;
  const ulonglong2* srcv = (const ulonglong2*)src;
  #pragma unroll
  for (int c = 0; c < 8; ++c) lkv[c * 512 + t] = srcv[c * 512 + t];
  __syncthreads();

  const int slot = t >> 5;                          // 0..15
  const int s    = t & 31;                          // slice 0..31
  const int kidx = (blockIdx.x << 5) + (slot << 1); // 2 owned keys
  const ull key0 = lk[kidx];
  const ull key1 = lk[kidx + 1];

  int cnt0 = 0, cnt1 = 0;
  const ulonglong2* lk2 = (const ulonglong2*)lk;    // 4096 pairs
  #pragma unroll 8
  for (int i = 0; i < 128; ++i) {
    ulonglong2 v = lk2[(i << 5) | s];
    cnt0 += (v.x < key0) ? 1 : 0;
    cnt0 += (v.y < key0) ? 1 : 0;
    cnt1 += (v.x < key1) ? 1 : 0;
    cnt1 += (v.y < key1) ? 1 : 0;
  }
  // reduce the 32 slice partials within each 32-lane half-wave (one slot each)
  cnt0 += __shfl_down(cnt0, 16, 32); cnt1 += __shfl_down(cnt1, 16, 32);
  cnt0 += __shfl_down(cnt0,  8, 32); cnt1 += __shfl_down(cnt1,  8, 32);
  cnt0 += __shfl_down(cnt0,  4, 32); cnt1 += __shfl_down(cnt1,  4, 32);
  cnt0 += __shfl_down(cnt0,  2, 32); cnt1 += __shfl_down(cnt1,  2, 32);
  cnt0 += __shfl_down(cnt0,  1, 32); cnt1 += __shfl_down(cnt1,  1, 32);
  if (s == 0) {                      // cnt = exact global rank in [0, 8192)
    dst[cnt0] = key0;
    dst[cnt1] = key1;
  }
}

// ---------------- K3 (r12, proven): fused group sums + dual PING-PONG scan ---------------
// 65 blocks x 1024 threads. Blocks 0..63: column c = blk; thread t = group g reads the
// group's 8 sorted keys (vectorized 4x ulonglong2, consumed in the same o=0..7 order) and
// gathers Wh[j][c] (L2-resident). Block 64: denominators. Scan: ping-pong buffers ->
// ONE barrier per round (10 vs 20); dst[t] = src[t] + src[t-off] performs exactly the
// additions of the in-place Hillis-Steele in the same order -> tables bitwise unchanged.
__global__ __launch_bounds__(1024) void k3_tables(float* __restrict__ ws) {
  __shared__ float sa[2][1024];
  __shared__ float sb[2][1024];
  const int t = threadIdx.x;
  const int blk = blockIdx.x;
  const ull* K = (const ull*)(ws + WS_KEYB);
  const float* Wh = ws + WS_WH;

  ull k8[8];
  {
    const ulonglong2* kp2 = (const ulonglong2*)(K + (t << 3));
    ulonglong2 q0 = kp2[0], q1 = kp2[1], q2 = kp2[2], q3 = kp2[3];
    k8[0] = q0.x; k8[1] = q0.y; k8[2] = q1.x; k8[3] = q1.y;
    k8[4] = q2.x; k8[5] = q2.y; k8[6] = q3.x; k8[7] = q3.y;
  }

  float s1 = 0.f, s2 = 0.f;
  if (blk < 64) {
    const int c = blk;
    #pragma unroll
    for (int o = 0; o < SBLK; ++o) {
      ull key = k8[o];
      float d = mono_dec((unsigned)(key >> 32));
      int j = (int)(key & 0xFFFFFFFFu);
      float e1 = __expf(d), e2 = __expf(LRELU_ALPHA * d);
      float v = Wh[j * F_OUT + c];
      s1 = fmaf(e1, v, s1); s2 = fmaf(e2, v, s2);
    }
  } else {
    #pragma unroll
    for (int o = 0; o < SBLK; ++o) {
      ull key = k8[o];
      float d = mono_dec((unsigned)(key >> 32));
      s1 += __expf(d); s2 += __expf(LRELU_ALPHA * d);
    }
  }

  const float xa = s1, xb = s2;
  sa[0][t] = xa; sb[0][t] = xb;
  __syncthreads();
  int cur = 0;
  #pragma unroll
  for (int off = 1; off < 1024; off <<= 1) {   // 10 rounds, 1 barrier each
    float va = sa[cur][t], vb = sb[cur][t];
    if (t >= off) { va += sa[cur][t - off]; vb += sb[cur][t - off]; }
    sa[cur ^ 1][t] = va;
    sb[cur ^ 1][t] = vb;
    __syncthreads();
    cur ^= 1;
  }
  const float ia = sa[cur][t], ib = sb[cur][t];
  const float ea = ia - xa, eb = ib - xb;

  if (blk < 64) {
    const int c = blk;
    ws[WS_P1 + t * F_OUT + c] = ea;
    ws[WS_P2 + t * F_OUT + c] = eb;
    if (t == NGRP - 1) {
      ws[WS_P1 + NGRP * F_OUT + c] = ia;
      ws[WS_P2 + NGRP * F_OUT + c] = ib;
    }
  } else {
    ws[WS_D1 + t] = ea;
    ws[WS_D2 + t] = eb;
    if (t == NGRP - 1) {
      ws[WS_D1 + NGRP] = ia;
      ws[WS_D2 + NGRP] = ib;
    }
  }
}

// ---------------- K4: 3-stage wave-ballot search + table lookup + residual + ELU ---------
// grid 2048 x 256. One wave per row, lane = output column. (proven)
__global__ __launch_bounds__(256) void k4_out(const float* __restrict__ ws,
                                              float* __restrict__ out) {
  const int t = threadIdx.x, wv = t >> 6, lane = t & 63;
  const int i = blockIdx.x * 4 + wv;
  const ull* K = (const ull*)(ws + WS_KEYB);
  const float s = ws[WS_ESRC + i];
  const float ns = (s == 0.0f) ? 0.0f : -s;   // canonicalize -0
  const unsigned Ki = mono_enc(ns);           // m > Ki  <=>  fl(s+d) > 0

  unsigned m1 = (unsigned)(K[lane << 7] >> 32);
  ull bal1 = __ballot(m1 <= Ki);
  int tl;
  if (bal1 == 0ull) {
    tl = 0;
  } else {
    int L1 = 63 - __clzll((long long)bal1);
    int base = L1 << 7;
    unsigned m2 = (unsigned)(K[base + (lane << 1)] >> 32);
    ull bal2 = __ballot(m2 <= Ki);
    int L2 = 63 - __clzll((long long)bal2);
    int p = base + (L2 << 1) + 1;
    unsigned m3 = (unsigned)(K[p] >> 32);
    tl = p + ((m3 <= Ki) ? 1 : 0);
  }
  const int b = tl >> 3, rr = tl & 7;

  float p1 = ws[WS_P1 + b * F_OUT + lane];
  float p2 = ws[WS_P2 + b * F_OUT + lane];
  float d1 = ws[WS_D1 + b], d2 = ws[WS_D2 + b];
  const float p1tot = ws[WS_P1 + NGRP * F_OUT + lane];
  const float d1tot = ws[WS_D1 + NGRP];
  const float* Wh = ws + WS_WH;

  for (int o = 0; o < rr; ++o) {               // <=7 residual elements
    ull key = K[(b << 3) + o];
    float d = mono_dec((unsigned)(key >> 32));
    int j = (int)(key & 0xFFFFFFFFu);
    float e1 = __expf(d), e2 = __expf(LRELU_ALPHA * d);
    float v = Wh[j * F_OUT + lane];            // coalesced 256B row
    p1 = fmaf(e1, v, p1); p2 = fmaf(e2, v, p2);
    d1 += e1; d2 += e2;
  }

  const float es1 = __expf(s), es2 = __expf(LRELU_ALPHA * s);
  const float num = es1 * (p1tot - p1) + es2 * p2;
  const float den = es1 * (d1tot - d1) + es2 * d2;
  const float r = num / den;
  out[i * F_OUT + lane] = (r > 0.f) ? r : (__expf(r) - 1.f);
}

extern "C" void kernel_launch(void* const* d_in, const int* in_sizes, int n_in,
                              void* d_out, int out_size, void* d_ws, size_t ws_size,
                              hipStream_t stream) {
  const float* h = (const float*)d_in[0];
  const float* W = (const float*)d_in[1];
  const float* a = (const float*)d_in[2];
  float* ws = (float*)d_ws;
  float* out = (float*)d_out;
  ull* keyA = (ull*)(ws + WS_KEYA);
  ull* keyB = (ull*)(ws + WS_KEYB);

  hipLaunchKernelGGL(k1_wh,     dim3(N_ROWS / 16), dim3(256),  0, stream, h, W, a, ws);
  hipLaunchKernelGGL(k2_sort,   dim3(256),         dim3(512),  0, stream, keyA, keyB);
  hipLaunchKernelGGL(k3_tables, dim3(65),          dim3(1024), 0, stream, ws);
  hipLaunchKernelGGL(k4_out,    dim3(N_ROWS / 4),  dim3(256),  0, stream, ws, out);
}